// Round 1
// baseline (215.003 us; speedup 1.0000x reference)
//
#include <hip/hip_runtime.h>

#define BATCH 131072
#define SN 32
#define H1 10
#define H2 6
#define TILE_ROWS 256
#define LDS_STRIDE 33   // +1 pad: bank = (row + s) % 32 -> 2-way (free)

__device__ __forceinline__ float fast_tanh(float x) {
    // tanh(x) = 1 - 2/(exp(2x)+1); v_exp_f32 + v_rcp_f32, abs err ~1e-6
    float e = __expf(2.0f * x);
    float r = __builtin_amdgcn_rcpf(e + 1.0f);
    return fmaf(-2.0f, r, 1.0f);
}

__global__ __launch_bounds__(256) void k_main(
    const float* __restrict__ x,
    const float* __restrict__ W1, const float* __restrict__ B1,
    const float* __restrict__ W2, const float* __restrict__ B2,
    const float* __restrict__ W3, const float* __restrict__ B3,
    float* __restrict__ out, double* __restrict__ acc /* [3][SN] */)
{
    __shared__ float xt[TILE_ROWS * LDS_STRIDE];
    const int tid = threadIdx.x;
    const int row0 = blockIdx.x * TILE_ROWS;

    // stage x tile (256 rows x 32 subnets) coalesced, transpose-pad into LDS
    const float4* xv = (const float4*)(x + (size_t)row0 * SN);
    #pragma unroll
    for (int it = 0; it < (TILE_ROWS * SN / 4) / 256; ++it) {
        int v = it * 256 + tid;
        float4 val = xv[v];
        int r = v >> 3;           // 8 float4 per row
        int c = (v & 7) << 2;
        float* dst = &xt[r * LDS_STRIDE + c];
        dst[0] = val.x; dst[1] = val.y; dst[2] = val.z; dst[3] = val.w;
    }
    __syncthreads();

    const int lane = tid & 63;
    const int wave = tid >> 6;    // 0..3

    #pragma unroll 1
    for (int si = 0; si < SN / 4; ++si) {
        // wave-uniform subnet id -> params land in SGPRs via s_load
        const int s = __builtin_amdgcn_readfirstlane(wave + si * 4);
        const float* w1p = W1 + s * H1;
        const float* b1p = B1 + s * H1;
        const float* w2p = W2 + s * H1 * H2;
        const float* b2p = B2 + s * H2;
        const float* w3p = W3 + s * H2;
        const float b3 = B3[s];

        float w1r[H1], b1r[H1];
        #pragma unroll
        for (int i = 0; i < H1; ++i) { w1r[i] = w1p[i]; b1r[i] = b1p[i]; }
        float w2r[H1 * H2];
        #pragma unroll
        for (int k = 0; k < H1 * H2; ++k) w2r[k] = w2p[k];
        float b2r[H2], w3r[H2];
        #pragma unroll
        for (int j = 0; j < H2; ++j) { b2r[j] = b2p[j]; w3r[j] = w3p[j]; }

        double s1 = 0.0, s2 = 0.0, s3 = 0.0;

        #pragma unroll 1
        for (int ch = 0; ch < TILE_ROWS / 64; ++ch) {
            const int r = ch * 64 + lane;
            const float xs = xt[r * LDS_STRIDE + s];

            float t[H1], p[H1], q[H1];
            #pragma unroll
            for (int i = 0; i < H1; ++i) {
                float u = fmaf(xs, w1r[i], b1r[i]);
                float ti = fast_tanh(u);
                float e = fmaf(-ti, ti, 1.0f);     // 1 - t^2
                t[i] = ti;
                p[i] = e * w1r[i];                  // dt/dx
                q[i] = -2.0f * ti * e * w1r[i] * w1r[i];  // d2t/dx2
            }

            float outv = b3, g2 = 0.0f;
            #pragma unroll
            for (int j = 0; j < H2; ++j) {
                float v = b2r[j], a = 0.0f, c = 0.0f;
                #pragma unroll
                for (int i = 0; i < H1; ++i) {
                    const float w = w2r[i * H2 + j];
                    v = fmaf(w, t[i], v);
                    a = fmaf(w, p[i], a);
                    c = fmaf(w, q[i], c);
                }
                float sj = fast_tanh(v);
                float dj = fmaf(-sj, sj, 1.0f);     // 1 - s^2
                float g2j = dj * c - 2.0f * sj * dj * a * a;
                outv = fmaf(w3r[j], sj, outv);
                g2   = fmaf(w3r[j], g2j, g2);
            }

            out[(size_t)(row0 + r) * SN + s] = outv;
            s1 += (double)outv;
            s2 += (double)outv * (double)outv;
            s3 += (double)g2 * (double)g2;
        }

        // wave butterfly reduce (64 lanes)
        #pragma unroll
        for (int off = 32; off > 0; off >>= 1) {
            s1 += __shfl_down(s1, off);
            s2 += __shfl_down(s2, off);
            s3 += __shfl_down(s3, off);
        }
        if (lane == 0) {
            atomicAdd(&acc[s], s1);
            atomicAdd(&acc[SN + s], s2);
            atomicAdd(&acc[2 * SN + s], s3);
        }
    }
}

__global__ void k_stats(const double* __restrict__ acc,
                        float* __restrict__ stats,   // [2][SN]: mean, inv_std
                        float* __restrict__ loss_out)
{
    const int s = threadIdx.x;
    __shared__ double pen[SN];
    if (s < SN) {
        const double invB = 1.0 / (double)BATCH;
        double mean = acc[s] * invB;
        double var = acc[SN + s] * invB - mean * mean;
        if (var < 0.0) var = 0.0;
        stats[s] = (float)mean;
        stats[SN + s] = (float)(1.0 / sqrt(var + 1e-10));
        pen[s] = (acc[2 * SN + s] * invB) / sqrt(var);
    }
    __syncthreads();
    if (s == 0) {
        double sum = 0.0;
        for (int i = 0; i < SN; ++i) sum += pen[i];
        loss_out[0] = (float)(0.001 * sum);
    }
}

__global__ __launch_bounds__(256) void k_norm(float* __restrict__ out,
                                              const float* __restrict__ stats)
{
    __shared__ float mean_s[SN], inv_s[SN];
    const int tid = threadIdx.x;
    if (tid < SN) { mean_s[tid] = stats[tid]; inv_s[tid] = stats[SN + tid]; }
    __syncthreads();
    const int v = blockIdx.x * 256 + tid;            // float4 index
    if (v < BATCH * SN / 4) {
        float4* p = (float4*)out;
        float4 val = p[v];
        const int c = (v & 7) << 2;                  // subnet base (8 float4/row)
        val.x = (val.x - mean_s[c + 0]) * inv_s[c + 0];
        val.y = (val.y - mean_s[c + 1]) * inv_s[c + 1];
        val.z = (val.z - mean_s[c + 2]) * inv_s[c + 2];
        val.w = (val.w - mean_s[c + 3]) * inv_s[c + 3];
        p[v] = val;
    }
}

extern "C" void kernel_launch(void* const* d_in, const int* in_sizes, int n_in,
                              void* d_out, int out_size, void* d_ws, size_t ws_size,
                              hipStream_t stream) {
    const float* x  = (const float*)d_in[0];
    const float* W1 = (const float*)d_in[1];
    const float* B1 = (const float*)d_in[2];
    const float* W2 = (const float*)d_in[3];
    const float* B2 = (const float*)d_in[4];
    const float* W3 = (const float*)d_in[5];
    const float* B3 = (const float*)d_in[6];

    float* out = (float*)d_out;                       // [BATCH*SN] out_bn, then [1] loss
    double* acc = (double*)d_ws;                      // [3][SN] doubles
    float* stats = (float*)((char*)d_ws + 3 * SN * sizeof(double)); // [2][SN]

    hipMemsetAsync(d_ws, 0, 3 * SN * sizeof(double), stream);

    k_main<<<BATCH / TILE_ROWS, 256, 0, stream>>>(x, W1, B1, W2, B2, W3, B3, out, acc);
    k_stats<<<1, 64, 0, stream>>>(acc, stats, out + (size_t)BATCH * SN);
    k_norm<<<(BATCH * SN / 4) / 256, 256, 0, stream>>>(out, stats);
}